// Round 1
// baseline (733.282 us; speedup 1.0000x reference)
//
#include <hip/hip_runtime.h>

#ifndef __has_builtin
#define __has_builtin(x) 0
#endif

// Problem constants (fixed by the reference):
constexpr int TN   = 1000;  // T
constexpr int BN   = 4096;  // B
constexpr int HID  = 32;    // hidden dim
constexpr int HH   = 15;    // func-net inner dim (padded to 16 in registers)
constexpr int OUTD = 8;     // output dim

__device__ __forceinline__ float fexp2(float x) {
#if __has_builtin(__builtin_amdgcn_exp2f)
  return __builtin_amdgcn_exp2f(x);
#else
  return exp2f(x);
#endif
}
__device__ __forceinline__ float frcp(float x) {
#if __has_builtin(__builtin_amdgcn_rcpf)
  return __builtin_amdgcn_rcpf(x);
#else
  return 1.0f / x;
#endif
}
// tanh(x) = 1 - 2/(exp2(x*2*log2e)+1); v_exp/v_rcp approx ~1ulp — far inside
// the 0.84 absmax threshold. Saturates correctly to +-1 for large |x|.
__device__ __forceinline__ float ftanh(float x) {
  float t = fexp2(x * 2.8853900817779268f);
  return fmaf(-2.0f, frcp(t + 1.0f), 1.0f);
}

// row_ror:K within the 16-lane DPP row; K must be a compile-time constant.
template <int K>
__device__ __forceinline__ float rotk(float x) {
  if constexpr (K == 0) {
    return x;
  } else {
    return __int_as_float(
        __builtin_amdgcn_mov_dpp(__float_as_int(x), 0x120 + K, 0xF, 0xF, true));
  }
}

#define REP16(M) M(0) M(1) M(2) M(3) M(4) M(5) M(6) M(7) \
                 M(8) M(9) M(10) M(11) M(12) M(13) M(14) M(15)

// 16 lanes per batch row (one DPP row == one batch row). 4096*16 = 65536
// threads = 1024 waves = 1 wave/SIMD across all 256 CUs.
__global__ __launch_bounds__(256, 1) void node_kernel(
    const float* __restrict__ times, const float* __restrict__ initial,
    const float* __restrict__ Wi, const float* __restrict__ bi,
    const float* __restrict__ Wf0, const float* __restrict__ bf0,
    const float* __restrict__ Wf1, const float* __restrict__ bf1,
    const float* __restrict__ Wf2, const float* __restrict__ bf2,
    const float* __restrict__ Wf3, const float* __restrict__ bf3,
    const float* __restrict__ Wl, const float* __restrict__ bl,
    float* __restrict__ out) {
  const int tid = blockIdx.x * 256 + threadIdx.x;
  const int row = tid >> 4;   // batch row, 0..4095
  const int q   = tid & 15;   // position within the 16-lane ring

  // --- DPP direction probe: after ror:1, lane q holds some neighbor's lane
  // index s1. If s1 == (q+1)&15 the HW pulls from higher lanes (dir=+1),
  // else from lower (dir=-1). Weight ring-ordering below uses the same dir,
  // so the kernel is correct under either hardware convention.
  int s1 = __builtin_amdgcn_mov_dpp(q, 0x121, 0xF, 0xF, true);
  const int dir = (s1 == ((q + 1) & 15)) ? 1 : -1;

  // --- per-lane weight registers, pre-rotated into ring order:
  // at rotation step k, this lane holds the h-pair / z value of lane
  // p = (q + dir*k) & 15, so it must multiply by the weights of row p.
  float w0r[16][2], w1r[16], w2r[16], w3r[16][2], wlr[16][2];
  const bool qv = (q < HH);
  float b0v = qv ? bf0[q] : 0.f;
  float b1v = qv ? bf1[q] : 0.f;
  float b2v = qv ? bf2[q] : 0.f;
  float b30 = bf3[2 * q + 0];
  float b31 = bf3[2 * q + 1];
  float blv = bl[q & 7];

#pragma unroll
  for (int k = 0; k < 16; ++k) {
    int p = (q + dir * k) & 15;
    bool pv = (p < HH);
    // layer0: neuron q (zero-padded for q==15), input components 2p, 2p+1
    w0r[k][0] = qv ? Wf0[(2 * p + 0) * HH + q] : 0.f;
    w0r[k][1] = qv ? Wf0[(2 * p + 1) * HH + q] : 0.f;
    // layers 1,2: neuron q, input z[p] (rows/cols >=15 are zero-padded)
    w1r[k] = (pv && qv) ? Wf1[p * HH + q] : 0.f;
    w2r[k] = (pv && qv) ? Wf2[p * HH + q] : 0.f;
    // layer3: output components 2q, 2q+1, input z2[p]
    w3r[k][0] = pv ? Wf3[p * HID + 2 * q + 0] : 0.f;
    w3r[k][1] = pv ? Wf3[p * HID + 2 * q + 1] : 0.f;
    // fused output projection: out neuron (q&7), input components 2p, 2p+1
    wlr[k][0] = Wl[(2 * p + 0) * OUTD + (q & 7)];
    wlr[k][1] = Wl[(2 * p + 1) * OUTD + (q & 7)];
  }

  // --- h0 = initial @ Wi + bi ; this lane owns components 2q, 2q+1
  float h0 = bi[2 * q + 0];
  float h1 = bi[2 * q + 1];
  {
    const float* ini = initial + (size_t)row * 16;
#pragma unroll
    for (int i = 0; i < 16; ++i) {
      float x = ini[i];
      h0 = fmaf(x, Wi[i * HID + 2 * q + 0], h0);
      h1 = fmaf(x, Wi[i * HID + 2 * q + 1], h1);
    }
  }

  float* op = out + (size_t)row * (TN * OUTD) + (q & 7);
  const bool do_store = (q < OUTD);

#pragma unroll 1
  for (int t = 0; t < TN; ++t) {
    // dt is wave-uniform; loaded early, consumed at the end of the step.
    float dtv = 0.0f;
    if (t + 1 < TN) dtv = times[t + 1] - times[t];

    // --- layer0 (z0[q]) + fused output projection, sharing h rotations.
    // Rotations are all from the ORIGINAL registers -> independent, no chain.
    float az[2] = {b0v, 0.f};
    float ao[2] = {blv, 0.f};
#define LP0(k)                                                               \
  {                                                                          \
    float hk0 = rotk<k>(h0), hk1 = rotk<k>(h1);                              \
    az[(k) & 1] = fmaf(hk1, w0r[k][1], fmaf(hk0, w0r[k][0], az[(k) & 1]));   \
    ao[(k) & 1] = fmaf(hk1, wlr[k][1], fmaf(hk0, wlr[k][0], ao[(k) & 1]));   \
  }
    REP16(LP0)
#undef LP0
    float z0 = ftanh(az[0] + az[1]);
    if (do_store) op[t * OUTD] = ao[0] + ao[1];

    // --- layer1
    float a1[2] = {b1v, 0.f};
#define LP1(k) { float zk = rotk<k>(z0); a1[(k) & 1] = fmaf(zk, w1r[k], a1[(k) & 1]); }
    REP16(LP1)
#undef LP1
    float z1 = ftanh(a1[0] + a1[1]);

    // --- layer2
    float a2[2] = {b2v, 0.f};
#define LP2(k) { float zk = rotk<k>(z1); a2[(k) & 1] = fmaf(zk, w2r[k], a2[(k) & 1]); }
    REP16(LP2)
#undef LP2
    float z2 = ftanh(a2[0] + a2[1]);

    // --- layer3 (back to 32-dim) + Euler update of owned components
    float y0[2] = {b30, 0.f}, y1[2] = {b31, 0.f};
#define LP3(k)                                                  \
  {                                                             \
    float zk = rotk<k>(z2);                                     \
    y0[(k) & 1] = fmaf(zk, w3r[k][0], y0[(k) & 1]);             \
    y1[(k) & 1] = fmaf(zk, w3r[k][1], y1[(k) & 1]);             \
  }
    REP16(LP3)
#undef LP3
    h0 = fmaf(dtv, y0[0] + y0[1], h0);
    h1 = fmaf(dtv, y1[0] + y1[1], h1);
  }
}

extern "C" void kernel_launch(void* const* d_in, const int* in_sizes, int n_in,
                              void* d_out, int out_size, void* d_ws, size_t ws_size,
                              hipStream_t stream) {
  (void)in_sizes; (void)n_in; (void)d_ws; (void)ws_size; (void)out_size;
  const float* times   = (const float*)d_in[0];
  const float* initial = (const float*)d_in[1];
  const float* Wi  = (const float*)d_in[2];
  const float* bi  = (const float*)d_in[3];
  const float* Wf0 = (const float*)d_in[4];
  const float* bf0 = (const float*)d_in[5];
  const float* Wf1 = (const float*)d_in[6];
  const float* bf1 = (const float*)d_in[7];
  const float* Wf2 = (const float*)d_in[8];
  const float* bf2 = (const float*)d_in[9];
  const float* Wf3 = (const float*)d_in[10];
  const float* bf3 = (const float*)d_in[11];
  const float* Wl  = (const float*)d_in[12];
  const float* bl  = (const float*)d_in[13];

  dim3 grid((BN * 16) / 256);  // 256 blocks -> 1 block/CU, 1 wave/SIMD
  dim3 block(256);
  hipLaunchKernelGGL(node_kernel, grid, block, 0, stream,
                     times, initial, Wi, bi, Wf0, bf0, Wf1, bf1,
                     Wf2, bf2, Wf3, bf3, Wl, bl, (float*)d_out);
}